// Round 8
// baseline (1727.375 us; speedup 1.0000x reference)
//
#include <hip/hip_runtime.h>
#include <hip/hip_fp16.h>
#include <stdint.h>

// SymmetricQuantLinear: out[m,n] = scale[n] * sum_k x[m,k] * (nib(k,n) - 8)
//   x: f32 [M][K] (fp16 values upconverted by harness), packed: int32 [K/2][N]
//   (1 byte/int: lo nibble = even k, hi = odd k), scale f32 [N]. Out f32 [M][N].
// Round 8: TWO-PASS.
//   Pass 1a: X f32 -> fp16 Xh in ws (exact).
//   Pass 1b: WP -> dequantized fp16 W^T [N][K] in ws (LDS-transpose, exact ints).
//   Pass 2:  pure fp16 GEMM, 128x128 tile, BK=64, 4 waves, pad-72 LDS rows,
//            single-barrier double-buffer (R7 structure), scale in epilogue.
// Fallback: if ws_size too small, run the validated R7 fused kernel.

#define M_DIM 4096
#define K_DIM 4096
#define N_DIM 11008
#define KH    (K_DIM / 2)            // 2048 packed rows / uint32 k-pairs per Wt row

#define WS_XH_BYTES  ((size_t)M_DIM * K_DIM * 2)            // 32 MiB
#define WS_WT_BYTES  ((size_t)N_DIM * KH * 4)               // ~86 MiB
#define WS_NEEDED    (WS_XH_BYTES + WS_WT_BYTES)

typedef __attribute__((ext_vector_type(8))) _Float16 f16x8;
typedef __attribute__((ext_vector_type(2))) _Float16 h2;
typedef __attribute__((ext_vector_type(4))) float f32x4;

__device__ __forceinline__ unsigned pack_f16_pair(float lo, float hi) {
    return __builtin_bit_cast(unsigned, __builtin_amdgcn_cvt_pkrtz(lo, hi));
}

__device__ __forceinline__ unsigned dq_pair(unsigned v) {
    // byte v = (hi<<4)|lo  ->  packed fp16 (lo-8, hi-8), exact.
    unsigned c = (v & 0xFu) | ((v << 12) & 0x000F0000u) | 0x64006400u;
    h2 r = __builtin_bit_cast(h2, c) + __builtin_bit_cast(h2, 0xE408E408u); // -=1032
    return __builtin_bit_cast(unsigned, r);
}

// ---- Pass 1a: X f32 -> fp16 (exact; values are fp16-origin) ----
__global__ void __launch_bounds__(256) cvt_x_kernel(
    const float* __restrict__ X, unsigned short* __restrict__ Xh)
{
    size_t i = ((size_t)blockIdx.x * 256 + threadIdx.x) * 8;   // 8192*256*8 == M*K
    float4 a = *(const float4*)(X + i);
    float4 b = *(const float4*)(X + i + 4);
    uint4 o = make_uint4(pack_f16_pair(a.x, a.y), pack_f16_pair(a.z, a.w),
                         pack_f16_pair(b.x, b.y), pack_f16_pair(b.z, b.w));
    *(uint4*)(Xh + i) = o;
}

// ---- Pass 1b: WP [KH][N] -> Wt uint32 [N][KH], Wt[n][r] = dq_pair(WP[r][n]) ----
__global__ void __launch_bounds__(256) dqt_kernel(
    const int* __restrict__ WP, unsigned* __restrict__ Wt)
{
    __shared__ unsigned Lt[64][65];          // [n-local][r-local], pad 1 (conflict-free)
    const int t = threadIdx.x;
    const int n0 = blockIdx.x * 64;          // 172 tiles
    const int r0 = blockIdx.y * 64;          // 32 tiles
    const int g = t >> 6, l = t & 63;
#pragma unroll
    for (int i = 0; i < 16; ++i) {
        const int r = r0 + g * 16 + i;
        Lt[l][g * 16 + i] = dq_pair((unsigned)WP[(size_t)r * N_DIM + n0 + l]);
    }
    __syncthreads();
    const int nr = t >> 2, sg = t & 3;
    unsigned* dst = Wt + (size_t)(n0 + nr) * KH + r0 + sg * 16;
#pragma unroll
    for (int c = 0; c < 4; ++c) {
        uint4 v = make_uint4(Lt[nr][sg * 16 + c * 4 + 0], Lt[nr][sg * 16 + c * 4 + 1],
                             Lt[nr][sg * 16 + c * 4 + 2], Lt[nr][sg * 16 + c * 4 + 3]);
        *(uint4*)(dst + c * 4) = v;
    }
}

// ---- Pass 2: pure fp16 GEMM, BK=64, single-barrier double-buffer ----
__global__ void __launch_bounds__(256) qgemm2_kernel(
    const unsigned short* __restrict__ Xh,   // fp16 [M][K]
    const unsigned*       __restrict__ Wt,   // uint32 [N][KH]  (fp16 [N][K])
    const float*          __restrict__ WS,   // [N]
    float*                __restrict__ Out)  // f32 [M][N]
{
    __shared__ unsigned short As[2][128 * 72];   // [m][k] fp16, stride 72 (pad 8)
    __shared__ unsigned short Bs[2][128 * 72];   // [n][k] fp16, stride 72 (pad 8)

    const int t = threadIdx.x;
    const int w = t >> 6;
    const int l = t & 63;

    // XCD swizzle: 2752 blocks, 2752/8 = 344 contiguous wgs per XCD.
    const int bid = blockIdx.x;
    const int wg  = (bid & 7) * 344 + (bid >> 3);
    const int by  = wg / 86;
    const int bx  = wg - by * 86;
    const int bm0 = by * 128;
    const int bn0 = bx * 128;

    const int wr = w >> 1;
    const int wc = w & 1;

    f32x4 acc[4][4];
#pragma unroll
    for (int i = 0; i < 4; ++i)
#pragma unroll
        for (int j = 0; j < 4; ++j)
            acc[i][j] = (f32x4){0.f, 0.f, 0.f, 0.f};

    // staging: thread t covers row t>>1, k-half t&1 (64B = 4 uint4) per operand
    const unsigned short* ga = Xh + (size_t)(bm0 + (t >> 1)) * K_DIM + (t & 1) * 32;
    const unsigned*       gb = Wt + (size_t)(bn0 + (t >> 1)) * KH   + (t & 1) * 16;
    const int awi = (t >> 1) * 72 + (t & 1) * 32;   // ushort index in As/Bs row

    const int lq = l >> 4;
    const int lr = l & 15;

    const int NT = K_DIM / 64;   // 64 K-steps

    uint4 sa[4], sb[4];          // single prefetch set (32 VGPR)

#define LOAD_SET(kt) do {                                                     \
    _Pragma("unroll")                                                         \
    for (int c = 0; c < 4; ++c) {                                             \
        sa[c] = *(const uint4*)(ga + (size_t)(kt) * 64 + c * 8);              \
        sb[c] = *(const uint4*)(gb + (size_t)(kt) * 32 + c * 4);              \
    }                                                                         \
} while (0)

#define WRITE_SET(buf) do {                                                   \
    _Pragma("unroll")                                                         \
    for (int c = 0; c < 4; ++c) {                                             \
        *(uint4*)(&As[buf][awi + c * 8]) = sa[c];                             \
        *(uint4*)(&Bs[buf][awi + c * 8]) = sb[c];                             \
    }                                                                         \
} while (0)

#define MFMA_STEP(buf) do {                                                   \
    _Pragma("unroll")                                                         \
    for (int h = 0; h < 2; ++h) {                                             \
        f16x8 _af[4], _bf[4];                                                 \
        _Pragma("unroll")                                                     \
        for (int mi = 0; mi < 4; ++mi)                                        \
            _af[mi] = *(const f16x8*)&As[buf][(wr * 64 + mi * 16 + lr) * 72 + h * 32 + lq * 8]; \
        _Pragma("unroll")                                                     \
        for (int ni = 0; ni < 4; ++ni)                                        \
            _bf[ni] = *(const f16x8*)&Bs[buf][(wc * 64 + ni * 16 + lr) * 72 + h * 32 + lq * 8]; \
        _Pragma("unroll")                                                     \
        for (int mi = 0; mi < 4; ++mi)                                        \
            _Pragma("unroll")                                                 \
            for (int ni = 0; ni < 4; ++ni)                                    \
                acc[mi][ni] = __builtin_amdgcn_mfma_f32_16x16x32_f16(         \
                    _af[mi], _bf[ni], acc[mi][ni], 0, 0, 0);                  \
    }                                                                         \
} while (0)

    // prologue: buf0 <- tile0; set <- tile1
    LOAD_SET(0);
    WRITE_SET(0);
    LOAD_SET(1);
    __syncthreads();

    for (int kt = 0; kt < NT; kt += 2) {
        // buf0 = tile kt, set = tile kt+1
        MFMA_STEP(0);
        WRITE_SET(1);                          // tile kt+1 -> buf1
        if (kt + 2 < NT) LOAD_SET(kt + 2);
        __syncthreads();
        MFMA_STEP(1);
        if (kt + 2 < NT) {
            WRITE_SET(0);                      // tile kt+2 -> buf0
            if (kt + 3 < NT) LOAD_SET(kt + 3);
        }
        __syncthreads();
    }

    // epilogue: per-column scale, f32 store
#pragma unroll
    for (int ni = 0; ni < 4; ++ni) {
        const int col = bn0 + wc * 64 + ni * 16 + lr;
        const float s = WS[col];
#pragma unroll
        for (int mi = 0; mi < 4; ++mi) {
            const int row = bm0 + wr * 64 + mi * 16 + lq * 4;
#pragma unroll
            for (int i = 0; i < 4; ++i) {
                Out[(size_t)(row + i) * N_DIM + col] = acc[mi][ni][i] * s;
            }
        }
    }
#undef LOAD_SET
#undef WRITE_SET
#undef MFMA_STEP
}

// ---- Fallback (validated R7): fused staging, used only if ws too small ----
__global__ void __launch_bounds__(256) qgemm_r7_kernel(
    const float* __restrict__ X, const int* __restrict__ WP,
    const float* __restrict__ WS, float* __restrict__ Out)
{
    __shared__ unsigned short As[2][128 * 40];
    __shared__ unsigned short Bs[2][128 * 40];
    const int t = threadIdx.x, w = t >> 6, l = t & 63;
    const int bid = blockIdx.x;
    const int wg  = (bid & 7) * 344 + (bid >> 3);
    const int by  = wg / 86, bx = wg - by * 86;
    const int bm0 = by * 128, bn0 = bx * 128;
    const int wr = w >> 1, wc = w & 1;
    f32x4 acc[4][4];
#pragma unroll
    for (int i = 0; i < 4; ++i)
#pragma unroll
        for (int j = 0; j < 4; ++j) acc[i][j] = (f32x4){0.f, 0.f, 0.f, 0.f};
    const int ar = t >> 2, ak = (t & 3) * 8;
    const float* xg = X + (size_t)(bm0 + ar) * K_DIM + ak;
    const int nl = 2 * l, rg = w;
    const int* wp0 = WP + (size_t)(rg * 4) * N_DIM + (bn0 + nl);
    const int lq = l >> 4, lr = l & 15;
    const int NT = K_DIM / 32;
    float4 sA0a, sA0b, sA1a, sA1b; int2 sP0[4];
    float4 tA0a, tA0b, tA1a, tA1b; int2 tP0[4];
#define LOAD_SETR(Aa, Ab, Ba, Bb, P, kt) do {                                 \
    const int _k = (kt) * 32;                                                 \
    Aa = *(const float4*)(xg + _k);                                           \
    Ab = *(const float4*)(xg + _k + 4);                                       \
    Ba = *(const float4*)(xg + (size_t)64 * K_DIM + _k);                      \
    Bb = *(const float4*)(xg + (size_t)64 * K_DIM + _k + 4);                  \
    P[0] = *(const int2*)(wp0 + ((size_t)(kt) * 16 + 0) * N_DIM);             \
    P[1] = *(const int2*)(wp0 + ((size_t)(kt) * 16 + 1) * N_DIM);             \
    P[2] = *(const int2*)(wp0 + ((size_t)(kt) * 16 + 2) * N_DIM);             \
    P[3] = *(const int2*)(wp0 + ((size_t)(kt) * 16 + 3) * N_DIM);             \
} while (0)
#define WRITE_SETR(Aa, Ab, Ba, Bb, P, buf) do {                               \
    uint4 _av0 = make_uint4(pack_f16_pair(Aa.x, Aa.y), pack_f16_pair(Aa.z, Aa.w), \
                            pack_f16_pair(Ab.x, Ab.y), pack_f16_pair(Ab.z, Ab.w)); \
    uint4 _av1 = make_uint4(pack_f16_pair(Ba.x, Ba.y), pack_f16_pair(Ba.z, Ba.w), \
                            pack_f16_pair(Bb.x, Bb.y), pack_f16_pair(Bb.z, Bb.w)); \
    *(uint4*)(&As[buf][(size_t)ar * 40 + ak])        = _av0;                  \
    *(uint4*)(&As[buf][(size_t)(64 + ar) * 40 + ak]) = _av1;                  \
    uint4 _bl = make_uint4(dq_pair((unsigned)P[0].x), dq_pair((unsigned)P[1].x), \
                           dq_pair((unsigned)P[2].x), dq_pair((unsigned)P[3].x)); \
    uint4 _bh = make_uint4(dq_pair((unsigned)P[0].y), dq_pair((unsigned)P[1].y), \
                           dq_pair((unsigned)P[2].y), dq_pair((unsigned)P[3].y)); \
    *(uint4*)(&Bs[buf][(size_t)nl * 40 + rg * 8])       = _bl;                \
    *(uint4*)(&Bs[buf][(size_t)(nl + 1) * 40 + rg * 8]) = _bh;                \
} while (0)
#define MFMA_STEPR(buf) do {                                                  \
    f16x8 _af[4], _bf[4];                                                     \
    _Pragma("unroll")                                                         \
    for (int mi = 0; mi < 4; ++mi)                                            \
        _af[mi] = *(const f16x8*)&As[buf][(size_t)(wr * 64 + mi * 16 + lr) * 40 + lq * 8]; \
    _Pragma("unroll")                                                         \
    for (int ni = 0; ni < 4; ++ni)                                            \
        _bf[ni] = *(const f16x8*)&Bs[buf][(size_t)(wc * 64 + ni * 16 + lr) * 40 + lq * 8]; \
    _Pragma("unroll")                                                         \
    for (int mi = 0; mi < 4; ++mi)                                            \
        _Pragma("unroll")                                                     \
        for (int ni = 0; ni < 4; ++ni)                                        \
            acc[mi][ni] = __builtin_amdgcn_mfma_f32_16x16x32_f16(             \
                _af[mi], _bf[ni], acc[mi][ni], 0, 0, 0);                      \
} while (0)
    LOAD_SETR(sA0a, sA0b, sA1a, sA1b, sP0, 0);
    WRITE_SETR(sA0a, sA0b, sA1a, sA1b, sP0, 0);
    LOAD_SETR(tA0a, tA0b, tA1a, tA1b, tP0, 1);
    __syncthreads();
    for (int kt = 0; kt < NT - 2; kt += 2) {
        MFMA_STEPR(0);
        WRITE_SETR(tA0a, tA0b, tA1a, tA1b, tP0, 1);
        LOAD_SETR(sA0a, sA0b, sA1a, sA1b, sP0, kt + 2);
        __syncthreads();
        MFMA_STEPR(1);
        WRITE_SETR(sA0a, sA0b, sA1a, sA1b, sP0, 0);
        LOAD_SETR(tA0a, tA0b, tA1a, tA1b, tP0, kt + 3);
        __syncthreads();
    }
    MFMA_STEPR(0);
    WRITE_SETR(tA0a, tA0b, tA1a, tA1b, tP0, 1);
    __syncthreads();
    MFMA_STEPR(1);
#pragma unroll
    for (int ni = 0; ni < 4; ++ni) {
        const int col = bn0 + wc * 64 + ni * 16 + lr;
        const float s = WS[col];
#pragma unroll
        for (int mi = 0; mi < 4; ++mi) {
            const int row = bm0 + wr * 64 + mi * 16 + lq * 4;
#pragma unroll
            for (int i = 0; i < 4; ++i)
                Out[(size_t)(row + i) * N_DIM + col] = acc[mi][ni][i] * s;
        }
    }
}

extern "C" void kernel_launch(void* const* d_in, const int* in_sizes, int n_in,
                              void* d_out, int out_size, void* d_ws, size_t ws_size,
                              hipStream_t stream) {
    const float* X  = (const float*)d_in[0];
    const int*   WP = (const int*)d_in[1];
    const float* WS = (const float*)d_in[2];
    float*       Out = (float*)d_out;

    if (ws_size >= WS_NEEDED) {
        unsigned short* Xh = (unsigned short*)d_ws;
        unsigned*       Wt = (unsigned*)((char*)d_ws + WS_XH_BYTES);
        cvt_x_kernel<<<(M_DIM * K_DIM) / (256 * 8), 256, 0, stream>>>(X, Xh);
        dim3 gdq(N_DIM / 64, KH / 64);                    // 172 x 32
        dqt_kernel<<<gdq, 256, 0, stream>>>(WP, Wt);
        dim3 grid((N_DIM / 128) * (M_DIM / 128));         // 2752
        qgemm2_kernel<<<grid, 256, 0, stream>>>(Xh, Wt, WS, Out);
    } else {
        dim3 grid((N_DIM / 128) * (M_DIM / 128));
        qgemm_r7_kernel<<<grid, 256, 0, stream>>>(X, WP, WS, Out);
    }
}

// Round 9
// 591.248 us; speedup vs baseline: 2.9216x; 2.9216x over previous
//
#include <hip/hip_runtime.h>
#include <hip/hip_fp16.h>
#include <stdint.h>

// SymmetricQuantLinear: out[m,n] = scale[n] * sum_k x[m,k] * (nib(k,n) - 8)
//   x: f32 [M][K] (fp16-origin values), packed: int32 [K/2][N] (1 byte/int:
//   lo nibble = even k, hi = odd k), scale f32 [N]. Out f32 [M][N].
// Round 9: two-pass (R8 prepasses, validated) + lean GEMM:
//   R7-proven geometry: 128x128, BK=32, 4 waves, 40KB LDS (4 blocks/CU),
//   single-barrier double-buffer, peeled tail, NO conditionals in loop.
//   Staging = raw uint4 copies (dequant/cvt hoisted to prepass).
//   __launch_bounds__(256,2) pins a 256-VGPR budget (R8 spilled at BK=64).

#define M_DIM 4096
#define K_DIM 4096
#define N_DIM 11008
#define KH    (K_DIM / 2)            // uint32 k-pairs per Wt row

#define WS_XH_BYTES  ((size_t)M_DIM * K_DIM * 2)            // 32 MiB
#define WS_WT_BYTES  ((size_t)N_DIM * KH * 4)               // ~86 MiB
#define WS_NEEDED    (WS_XH_BYTES + WS_WT_BYTES)

typedef __attribute__((ext_vector_type(8))) _Float16 f16x8;
typedef __attribute__((ext_vector_type(2))) _Float16 h2;
typedef __attribute__((ext_vector_type(4))) float f32x4;

__device__ __forceinline__ unsigned pack_f16_pair(float lo, float hi) {
    return __builtin_bit_cast(unsigned, __builtin_amdgcn_cvt_pkrtz(lo, hi));
}

__device__ __forceinline__ unsigned dq_pair(unsigned v) {
    // byte v = (hi<<4)|lo  ->  packed fp16 (lo-8, hi-8), exact.
    unsigned c = (v & 0xFu) | ((v << 12) & 0x000F0000u) | 0x64006400u;
    h2 r = __builtin_bit_cast(h2, c) + __builtin_bit_cast(h2, 0xE408E408u); // -=1032
    return __builtin_bit_cast(unsigned, r);
}

// ---- Pass 1a: X f32 -> fp16 (exact) ----
__global__ void __launch_bounds__(256) cvt_x_kernel(
    const float* __restrict__ X, unsigned short* __restrict__ Xh)
{
    size_t i = ((size_t)blockIdx.x * 256 + threadIdx.x) * 8;
    float4 a = *(const float4*)(X + i);
    float4 b = *(const float4*)(X + i + 4);
    uint4 o = make_uint4(pack_f16_pair(a.x, a.y), pack_f16_pair(a.z, a.w),
                         pack_f16_pair(b.x, b.y), pack_f16_pair(b.z, b.w));
    *(uint4*)(Xh + i) = o;
}

// ---- Pass 1b: WP [KH][N] -> Wt uint32 [N][KH], Wt[n][r] = dq_pair(WP[r][n]) ----
__global__ void __launch_bounds__(256) dqt_kernel(
    const int* __restrict__ WP, unsigned* __restrict__ Wt)
{
    __shared__ unsigned Lt[64][65];
    const int t = threadIdx.x;
    const int n0 = blockIdx.x * 64;
    const int r0 = blockIdx.y * 64;
    const int g = t >> 6, l = t & 63;
#pragma unroll
    for (int i = 0; i < 16; ++i) {
        const int r = r0 + g * 16 + i;
        Lt[l][g * 16 + i] = dq_pair((unsigned)WP[(size_t)r * N_DIM + n0 + l]);
    }
    __syncthreads();
    const int nr = t >> 2, sg = t & 3;
    unsigned* dst = Wt + (size_t)(n0 + nr) * KH + r0 + sg * 16;
#pragma unroll
    for (int c = 0; c < 4; ++c) {
        uint4 v = make_uint4(Lt[nr][sg * 16 + c * 4 + 0], Lt[nr][sg * 16 + c * 4 + 1],
                             Lt[nr][sg * 16 + c * 4 + 2], Lt[nr][sg * 16 + c * 4 + 3]);
        *(uint4*)(dst + c * 4) = v;
    }
}

// ---- Pass 2: pure fp16 GEMM, BK=32, single-barrier double-buffer ----
__global__ void __launch_bounds__(256, 2) qgemm2_kernel(
    const unsigned short* __restrict__ Xh,   // fp16 [M][K]
    const unsigned*       __restrict__ Wt,   // uint32 [N][KH] (fp16 [N][K])
    const float*          __restrict__ WS,   // [N]
    float*                __restrict__ Out)  // f32 [M][N]
{
    __shared__ unsigned short As[2][128 * 40];   // [m][k] fp16, stride 40
    __shared__ unsigned short Bs[2][128 * 40];   // [n][k] fp16, stride 40

    const int t = threadIdx.x;
    const int w = t >> 6;
    const int l = t & 63;

    // XCD swizzle: 2752 blocks, 2752/8 = 344 contiguous wgs per XCD.
    const int bid = blockIdx.x;
    const int wg  = (bid & 7) * 344 + (bid >> 3);
    const int by  = wg / 86;
    const int bx  = wg - by * 86;
    const int bm0 = by * 128;
    const int bn0 = bx * 128;

    const int wr = w >> 1;
    const int wc = w & 1;

    f32x4 acc[4][4];
#pragma unroll
    for (int i = 0; i < 4; ++i)
#pragma unroll
        for (int j = 0; j < 4; ++j)
            acc[i][j] = (f32x4){0.f, 0.f, 0.f, 0.f};

    // staging: thread t covers row t>>1 (0..127), k-half (t&1): 32 B each op
    const unsigned short* ga = Xh + (size_t)(bm0 + (t >> 1)) * K_DIM + (t & 1) * 16;
    const unsigned*       gb = Wt + (size_t)(bn0 + (t >> 1)) * KH   + (t & 1) * 8;
    const int awi = (t >> 1) * 40 + (t & 1) * 16;   // ushort index

    const int lq = l >> 4;
    const int lr = l & 15;

    const int NT = K_DIM / 32;   // 128 K-steps

    uint4 sa0, sa1, sb0, sb1;    // 16 VGPR prefetch set

#define LOAD_SET(kt) do {                                                     \
    sa0 = *(const uint4*)(ga + (size_t)(kt) * 32);                            \
    sa1 = *(const uint4*)(ga + (size_t)(kt) * 32 + 8);                        \
    sb0 = *(const uint4*)(gb + (size_t)(kt) * 16);                            \
    sb1 = *(const uint4*)(gb + (size_t)(kt) * 16 + 4);                        \
} while (0)

#define WRITE_SET(buf) do {                                                   \
    *(uint4*)(&As[buf][awi])     = sa0;                                       \
    *(uint4*)(&As[buf][awi + 8]) = sa1;                                       \
    *(uint4*)(&Bs[buf][awi])     = sb0;                                       \
    *(uint4*)(&Bs[buf][awi + 8]) = sb1;                                       \
} while (0)

#define MFMA_STEP(buf) do {                                                   \
    f16x8 _af[4], _bf[4];                                                     \
    _Pragma("unroll")                                                         \
    for (int mi = 0; mi < 4; ++mi)                                            \
        _af[mi] = *(const f16x8*)&As[buf][(wr * 64 + mi * 16 + lr) * 40 + lq * 8]; \
    _Pragma("unroll")                                                         \
    for (int ni = 0; ni < 4; ++ni)                                            \
        _bf[ni] = *(const f16x8*)&Bs[buf][(wc * 64 + ni * 16 + lr) * 40 + lq * 8]; \
    _Pragma("unroll")                                                         \
    for (int mi = 0; mi < 4; ++mi)                                            \
        _Pragma("unroll")                                                     \
        for (int ni = 0; ni < 4; ++ni)                                        \
            acc[mi][ni] = __builtin_amdgcn_mfma_f32_16x16x32_f16(             \
                _af[mi], _bf[ni], acc[mi][ni], 0, 0, 0);                      \
} while (0)

    // prologue: buf0 <- tile0; prefetch tile1
    LOAD_SET(0);
    WRITE_SET(0);
    LOAD_SET(1);
    __syncthreads();

    // main loop (steps 0..125), peeled tail, no conditionals inside
    for (int kt = 0; kt < NT - 2; kt += 2) {
        MFMA_STEP(0);
        WRITE_SET(1);            // tile kt+1 -> buf1
        LOAD_SET(kt + 2);
        __syncthreads();
        MFMA_STEP(1);
        WRITE_SET(0);            // tile kt+2 -> buf0
        LOAD_SET(kt + 3);
        __syncthreads();
    }
    MFMA_STEP(0);
    WRITE_SET(1);                // tile 127 -> buf1 (loaded as "kt+3" = 127)
    __syncthreads();
    MFMA_STEP(1);

    // epilogue: per-column scale, f32 store
#pragma unroll
    for (int ni = 0; ni < 4; ++ni) {
        const int col = bn0 + wc * 64 + ni * 16 + lr;
        const float s = WS[col];
#pragma unroll
        for (int mi = 0; mi < 4; ++mi) {
            const int row = bm0 + wr * 64 + mi * 16 + lq * 4;
#pragma unroll
            for (int i = 0; i < 4; ++i) {
                Out[(size_t)(row + i) * N_DIM + col] = acc[mi][ni][i] * s;
            }
        }
    }
#undef LOAD_SET
#undef WRITE_SET
#undef MFMA_STEP
}

extern "C" void kernel_launch(void* const* d_in, const int* in_sizes, int n_in,
                              void* d_out, int out_size, void* d_ws, size_t ws_size,
                              hipStream_t stream) {
    const float* X  = (const float*)d_in[0];
    const int*   WP = (const int*)d_in[1];
    const float* WS = (const float*)d_in[2];
    float*       Out = (float*)d_out;

    unsigned short* Xh = (unsigned short*)d_ws;
    unsigned*       Wt = (unsigned*)((char*)d_ws + WS_XH_BYTES);

    cvt_x_kernel<<<(M_DIM * K_DIM) / (256 * 8), 256, 0, stream>>>(X, Xh);
    dim3 gdq(N_DIM / 64, KH / 64);                    // 172 x 32
    dqt_kernel<<<gdq, 256, 0, stream>>>(WP, Wt);
    dim3 grid((N_DIM / 128) * (M_DIM / 128));         // 2752
    qgemm2_kernel<<<grid, 256, 0, stream>>>(Xh, Wt, WS, Out);
}

// Round 10
// 557.230 us; speedup vs baseline: 3.0999x; 1.0610x over previous
//
#include <hip/hip_runtime.h>
#include <hip/hip_fp16.h>
#include <stdint.h>

// SymmetricQuantLinear: out[m,n] = scale[n] * sum_k x[m,k] * (nib(k,n) - 8)
//   x: f32 [M][K] (fp16-origin), packed: int32 [K/2][N] (lo nib = even k),
//   scale f32 [N]. Out f32 [M][N].
// Round 10: two-pass (validated prepasses) + m97-structure GEMM:
//   128x128, BK=32, 4 waves, global_load_lds staging (no reg round-trip,
//   no ds_writes), LINEAR LDS dest + SOURCE-pre-swizzled global addr
//   (byte ^= ((row>>1)&3)<<4) so frag ds_read_b128 is 2-way (free).
//   Single barrier per K-step (R7/R9-proven sync), scale in epilogue.

#define M_DIM 4096
#define K_DIM 4096
#define N_DIM 11008
#define KH    (K_DIM / 2)

#define WS_XH_BYTES  ((size_t)M_DIM * K_DIM * 2)            // 32 MiB
#define WS_WT_BYTES  ((size_t)N_DIM * KH * 4)               // ~86 MiB

typedef __attribute__((ext_vector_type(8))) _Float16 f16x8;
typedef __attribute__((ext_vector_type(2))) _Float16 h2;
typedef __attribute__((ext_vector_type(4))) float f32x4;

__device__ __forceinline__ unsigned pack_f16_pair(float lo, float hi) {
    return __builtin_bit_cast(unsigned, __builtin_amdgcn_cvt_pkrtz(lo, hi));
}

__device__ __forceinline__ unsigned dq_pair(unsigned v) {
    // byte v = (hi<<4)|lo  ->  packed fp16 (lo-8, hi-8), exact.
    unsigned c = (v & 0xFu) | ((v << 12) & 0x000F0000u) | 0x64006400u;
    h2 r = __builtin_bit_cast(h2, c) + __builtin_bit_cast(h2, 0xE408E408u);
    return __builtin_bit_cast(unsigned, r);
}

__device__ __forceinline__ void gld_lds16(const void* g, void* l) {
    __builtin_amdgcn_global_load_lds(
        (const __attribute__((address_space(1))) unsigned int*)g,
        (__attribute__((address_space(3))) unsigned int*)l,
        16, 0, 0);
}

// ---- Pass 1a: X f32 -> fp16 (exact) ----
__global__ void __launch_bounds__(256) cvt_x_kernel(
    const float* __restrict__ X, unsigned short* __restrict__ Xh)
{
    size_t i = ((size_t)blockIdx.x * 256 + threadIdx.x) * 8;
    float4 a = *(const float4*)(X + i);
    float4 b = *(const float4*)(X + i + 4);
    uint4 o = make_uint4(pack_f16_pair(a.x, a.y), pack_f16_pair(a.z, a.w),
                         pack_f16_pair(b.x, b.y), pack_f16_pair(b.z, b.w));
    *(uint4*)(Xh + i) = o;
}

// ---- Pass 1b: WP [KH][N] -> Wt uint32 [N][KH] (fp16 [N][K] transposed) ----
__global__ void __launch_bounds__(256) dqt_kernel(
    const int* __restrict__ WP, unsigned* __restrict__ Wt)
{
    __shared__ unsigned Lt[64][65];
    const int t = threadIdx.x;
    const int n0 = blockIdx.x * 64;
    const int r0 = blockIdx.y * 64;
    const int g = t >> 6, l = t & 63;
#pragma unroll
    for (int i = 0; i < 16; ++i) {
        const int r = r0 + g * 16 + i;
        Lt[l][g * 16 + i] = dq_pair((unsigned)WP[(size_t)r * N_DIM + n0 + l]);
    }
    __syncthreads();
    const int nr = t >> 2, sg = t & 3;
    unsigned* dst = Wt + (size_t)(n0 + nr) * KH + r0 + sg * 16;
#pragma unroll
    for (int c = 0; c < 4; ++c) {
        uint4 v = make_uint4(Lt[nr][sg * 16 + c * 4 + 0], Lt[nr][sg * 16 + c * 4 + 1],
                             Lt[nr][sg * 16 + c * 4 + 2], Lt[nr][sg * 16 + c * 4 + 3]);
        *(uint4*)(dst + c * 4) = v;
    }
}

// ---- Pass 2: fp16 GEMM, gload_lds staging, swizzled LDS ----
__global__ void __launch_bounds__(256, 4) qgemm3_kernel(
    const unsigned short* __restrict__ Xh,   // fp16 [M][K]
    const unsigned*       __restrict__ Wt,   // uint32 [N][KH] (fp16 [N][K])
    const float*          __restrict__ WS,   // [N]
    float*                __restrict__ Out)  // f32 [M][N]
{
    __shared__ unsigned short As[2][128 * 32];   // linear [m][k], 8 KB each buf
    __shared__ unsigned short Bs[2][128 * 32];   // linear [n][k]

    const int t = threadIdx.x;
    const int w = t >> 6;
    const int l = t & 63;

    // XCD swizzle: 2752 blocks, 344 contiguous wgs per XCD.
    const int bid = blockIdx.x;
    const int wg  = (bid & 7) * 344 + (bid >> 3);
    const int by  = wg / 86;
    const int bx  = wg - by * 86;
    const int bm0 = by * 128;
    const int bn0 = bx * 128;

    const int wr = w >> 1;
    const int wc = w & 1;

    f32x4 acc[4][4];
#pragma unroll
    for (int i = 0; i < 4; ++i)
#pragma unroll
        for (int j = 0; j < 4; ++j)
            acc[i][j] = (f32x4){0.f, 0.f, 0.f, 0.f};

    // ---- staging addresses (source-pre-swizzled; LDS dest linear) ----
    // call i in {0,1}: row = i*64 + (t>>2); 16B slot c0 = t&3;
    // swizzled source slot cS = c0 ^ ((row>>1)&3).
    const int r0a = (t >> 2);            // call-0 row (call-1: +64)
    const int c0  = t & 3;
    const int rowA0 = r0a,      rowA1 = r0a + 64;
    const int cS0 = c0 ^ ((rowA0 >> 1) & 3);
    const int cS1 = c0 ^ ((rowA1 >> 1) & 3);
    // A source: Xh[(bm0+row)*K + kt*32 + cS*8]   (8 ushorts = 16 B)
    const unsigned short* gA0 = Xh + (size_t)(bm0 + rowA0) * K_DIM + cS0 * 8;
    const unsigned short* gA1 = Xh + (size_t)(bm0 + rowA1) * K_DIM + cS1 * 8;
    // B source: Wt[(bn0+row)*KH + kt*16 + cS*4]  (4 uints = 16 B)
    const unsigned* gB0 = Wt + (size_t)(bn0 + rowA0) * KH + cS0 * 4;
    const unsigned* gB1 = Wt + (size_t)(bn0 + rowA1) * KH + cS1 * 4;
    // LDS dests (ushort idx): linear o/2 = t*8 (+ call*2048)
    const int ldst = t * 8;

#define STAGE(buf, kt) do {                                                   \
    gld_lds16(gA0 + (size_t)(kt) * 32, &As[buf][ldst]);                       \
    gld_lds16(gA1 + (size_t)(kt) * 32, &As[buf][ldst + 2048]);                \
    gld_lds16(gB0 + (size_t)(kt) * 16, &Bs[buf][ldst]);                       \
    gld_lds16(gB1 + (size_t)(kt) * 16, &Bs[buf][ldst + 2048]);                \
} while (0)

    const int lq = l >> 4;
    const int lr = l & 15;

    // frag read (swizzled): ushort idx = row*32 + (lq ^ ((row>>1)&3))*8
#define MFMA_STEP(buf) do {                                                   \
    f16x8 _af[4], _bf[4];                                                     \
    _Pragma("unroll")                                                         \
    for (int mi = 0; mi < 4; ++mi) {                                          \
        const int _r = wr * 64 + mi * 16 + lr;                                \
        _af[mi] = *(const f16x8*)&As[buf][_r * 32 + (lq ^ ((_r >> 1) & 3)) * 8]; \
    }                                                                         \
    _Pragma("unroll")                                                         \
    for (int ni = 0; ni < 4; ++ni) {                                          \
        const int _r = wc * 64 + ni * 16 + lr;                                \
        _bf[ni] = *(const f16x8*)&Bs[buf][_r * 32 + (lq ^ ((_r >> 1) & 3)) * 8]; \
    }                                                                         \
    _Pragma("unroll")                                                         \
    for (int mi = 0; mi < 4; ++mi)                                            \
        _Pragma("unroll")                                                     \
        for (int ni = 0; ni < 4; ++ni)                                        \
            acc[mi][ni] = __builtin_amdgcn_mfma_f32_16x16x32_f16(             \
                _af[mi], _bf[ni], acc[mi][ni], 0, 0, 0);                      \
} while (0)

    const int NT = K_DIM / 32;   // 128

    // prologue
    STAGE(0, 0);
    asm volatile("s_waitcnt vmcnt(0)" ::: "memory");
    __syncthreads();

    // main loop: stage next tile into other buffer, compute current,
    // drain DMA + one barrier.
    for (int kt = 0; kt < NT - 1; ++kt) {
        const int cur = kt & 1;
        STAGE(cur ^ 1, kt + 1);
        MFMA_STEP(cur);
        asm volatile("s_waitcnt vmcnt(0)" ::: "memory");
        __syncthreads();
    }
    MFMA_STEP((NT - 1) & 1);

    // epilogue: per-column scale, f32 store
#pragma unroll
    for (int ni = 0; ni < 4; ++ni) {
        const int col = bn0 + wc * 64 + ni * 16 + lr;
        const float s = WS[col];
#pragma unroll
        for (int mi = 0; mi < 4; ++mi) {
            const int row = bm0 + wr * 64 + mi * 16 + lq * 4;
#pragma unroll
            for (int i = 0; i < 4; ++i) {
                Out[(size_t)(row + i) * N_DIM + col] = acc[mi][ni][i] * s;
            }
        }
    }
#undef STAGE
#undef MFMA_STEP
}

extern "C" void kernel_launch(void* const* d_in, const int* in_sizes, int n_in,
                              void* d_out, int out_size, void* d_ws, size_t ws_size,
                              hipStream_t stream) {
    const float* X  = (const float*)d_in[0];
    const int*   WP = (const int*)d_in[1];
    const float* WS = (const float*)d_in[2];
    float*       Out = (float*)d_out;

    unsigned short* Xh = (unsigned short*)d_ws;
    unsigned*       Wt = (unsigned*)((char*)d_ws + WS_XH_BYTES);

    cvt_x_kernel<<<(M_DIM * K_DIM) / (256 * 8), 256, 0, stream>>>(X, Xh);
    dim3 gdq(N_DIM / 64, KH / 64);                    // 172 x 32
    dqt_kernel<<<gdq, 256, 0, stream>>>(WP, Wt);
    dim3 grid((N_DIM / 128) * (M_DIM / 128));         // 2752
    qgemm3_kernel<<<grid, 256, 0, stream>>>(Xh, Wt, WS, Out);
}

// Round 11
// 491.888 us; speedup vs baseline: 3.5117x; 1.1328x over previous
//
#include <hip/hip_runtime.h>
#include <hip/hip_fp16.h>
#include <stdint.h>

// SymmetricQuantLinear: out[m,n] = scale[n] * sum_k x[m,k] * (nib(k,n) - 8)
//   x: f32 [M][K] (fp16-origin), packed: int32 [K/2][N], scale f32 [N].
//   Out f32 [M][N].
// Round 11: two-pass (validated prepasses) + DEEP-PIPELINED GEMM:
//   256x256 tile, BK=32, 8 waves (2Mx4N), 3 LDS K-tile slots (96 KB),
//   counted s_waitcnt vmcnt(8) (never 0 in main loop) + raw s_barrier pairs,
//   global_load_lds staging with R10-validated source-pre-swizzle
//   (0 bank conflicts), static x3 slot unroll, setprio around MFMA.

#define M_DIM 4096
#define K_DIM 4096
#define N_DIM 11008
#define KH    (K_DIM / 2)

#define WS_XH_BYTES  ((size_t)M_DIM * K_DIM * 2)            // 32 MiB

typedef __attribute__((ext_vector_type(8))) _Float16 f16x8;
typedef __attribute__((ext_vector_type(2))) _Float16 h2;
typedef __attribute__((ext_vector_type(4))) float f32x4;

__device__ __forceinline__ unsigned pack_f16_pair(float lo, float hi) {
    return __builtin_bit_cast(unsigned, __builtin_amdgcn_cvt_pkrtz(lo, hi));
}

__device__ __forceinline__ unsigned dq_pair(unsigned v) {
    // byte v = (hi<<4)|lo  ->  packed fp16 (lo-8, hi-8), exact.
    unsigned c = (v & 0xFu) | ((v << 12) & 0x000F0000u) | 0x64006400u;
    h2 r = __builtin_bit_cast(h2, c) + __builtin_bit_cast(h2, 0xE408E408u);
    return __builtin_bit_cast(unsigned, r);
}

__device__ __forceinline__ void gld_lds16(const void* g, void* l) {
    __builtin_amdgcn_global_load_lds(
        (const __attribute__((address_space(1))) unsigned int*)g,
        (__attribute__((address_space(3))) unsigned int*)l,
        16, 0, 0);
}

// ---- Pass 1a: X f32 -> fp16 (exact) ----
__global__ void __launch_bounds__(256) cvt_x_kernel(
    const float* __restrict__ X, unsigned short* __restrict__ Xh)
{
    size_t i = ((size_t)blockIdx.x * 256 + threadIdx.x) * 8;
    float4 a = *(const float4*)(X + i);
    float4 b = *(const float4*)(X + i + 4);
    uint4 o = make_uint4(pack_f16_pair(a.x, a.y), pack_f16_pair(a.z, a.w),
                         pack_f16_pair(b.x, b.y), pack_f16_pair(b.z, b.w));
    *(uint4*)(Xh + i) = o;
}

// ---- Pass 1b: WP [KH][N] -> Wt uint32 [N][KH] (fp16 [N][K] transposed) ----
__global__ void __launch_bounds__(256) dqt_kernel(
    const int* __restrict__ WP, unsigned* __restrict__ Wt)
{
    __shared__ unsigned Lt[64][65];
    const int t = threadIdx.x;
    const int n0 = blockIdx.x * 64;
    const int r0 = blockIdx.y * 64;
    const int g = t >> 6, l = t & 63;
#pragma unroll
    for (int i = 0; i < 16; ++i) {
        const int r = r0 + g * 16 + i;
        Lt[l][g * 16 + i] = dq_pair((unsigned)WP[(size_t)r * N_DIM + n0 + l]);
    }
    __syncthreads();
    const int nr = t >> 2, sg = t & 3;
    unsigned* dst = Wt + (size_t)(n0 + nr) * KH + r0 + sg * 16;
#pragma unroll
    for (int c = 0; c < 4; ++c) {
        uint4 v = make_uint4(Lt[nr][sg * 16 + c * 4 + 0], Lt[nr][sg * 16 + c * 4 + 1],
                             Lt[nr][sg * 16 + c * 4 + 2], Lt[nr][sg * 16 + c * 4 + 3]);
        *(uint4*)(dst + c * 4) = v;
    }
}

// ---- Pass 2: deep-pipelined fp16 GEMM ----
__global__ void __launch_bounds__(512, 2) qgemm4_kernel(
    const unsigned short* __restrict__ Xh,   // fp16 [M][K]
    const unsigned*       __restrict__ Wt,   // uint32 [N][KH] (fp16 [N][K])
    const float*          __restrict__ WS,   // [N]
    float*                __restrict__ Out)  // f32 [M][N]
{
    __shared__ unsigned short As[3][256 * 32];   // 16 KB per slot
    __shared__ unsigned short Bs[3][256 * 32];   // 96 KB total

    const int t = threadIdx.x;     // 0..511
    const int w = t >> 6;          // wave 0..7
    const int l = t & 63;

    // XCD swizzle: 688 blocks = 8 * 86 (bijective).
    const int bid = blockIdx.x;
    const int wg  = (bid & 7) * 86 + (bid >> 3);
    const int by  = wg / 43;                 // 0..15
    const int bx  = wg - by * 43;            // 0..42
    const int bm0 = by * 256;
    const int bn0 = bx * 256;

    const int wr = w >> 2;         // 0..1  -> 128 rows
    const int wc = w & 3;          // 0..3  -> 64 cols

    f32x4 acc[8][4];
#pragma unroll
    for (int i = 0; i < 8; ++i)
#pragma unroll
        for (int j = 0; j < 4; ++j)
            acc[i][j] = (f32x4){0.f, 0.f, 0.f, 0.f};

    // ---- staging (source-pre-swizzled, LDS dest linear; R10-validated) ----
    // load j in {0,1}: row = (t>>2) + j*128; 16B slot c0 = t&3;
    // cS = c0 ^ ((row>>1)&3); note ((r+128)>>1)&3 == ((r>>1)&3) -> same cS.
    const int r0 = t >> 2;
    const int c0 = t & 3;
    const int cS = c0 ^ ((r0 >> 1) & 3);
    const unsigned short* gA0 = Xh + (size_t)(bm0 + r0) * K_DIM + cS * 8;
    const unsigned short* gA1 = Xh + (size_t)(bm0 + r0 + 128) * K_DIM + cS * 8;
    const unsigned*       gB0 = Wt + (size_t)(bn0 + r0) * KH + cS * 4;
    const unsigned*       gB1 = Wt + (size_t)(bn0 + r0 + 128) * KH + cS * 4;
    const int ldst = t * 8;        // ushort idx; +4096 for j=1

#define STAGE(s, kt) do {                                                     \
    gld_lds16(gA0 + (size_t)(kt) * 32, &As[s][ldst]);                         \
    gld_lds16(gA1 + (size_t)(kt) * 32, &As[s][ldst + 4096]);                  \
    gld_lds16(gB0 + (size_t)(kt) * 16, &Bs[s][ldst]);                         \
    gld_lds16(gB1 + (size_t)(kt) * 16, &Bs[s][ldst + 4096]);                  \
} while (0)

    const int lq = l >> 4;
    const int lr = l & 15;

#define MFMA_STEP(s) do {                                                     \
    f16x8 _af[8], _bf[4];                                                     \
    _Pragma("unroll")                                                         \
    for (int mi = 0; mi < 8; ++mi) {                                          \
        const int _r = wr * 128 + mi * 16 + lr;                               \
        _af[mi] = *(const f16x8*)&As[s][_r * 32 + (lq ^ ((_r >> 1) & 3)) * 8]; \
    }                                                                         \
    _Pragma("unroll")                                                         \
    for (int ni = 0; ni < 4; ++ni) {                                          \
        const int _r = wc * 64 + ni * 16 + lr;                                \
        _bf[ni] = *(const f16x8*)&Bs[s][_r * 32 + (lq ^ ((_r >> 1) & 3)) * 8]; \
    }                                                                         \
    __builtin_amdgcn_s_setprio(1);                                            \
    _Pragma("unroll")                                                         \
    for (int mi = 0; mi < 8; ++mi)                                            \
        _Pragma("unroll")                                                     \
        for (int ni = 0; ni < 4; ++ni)                                        \
            acc[mi][ni] = __builtin_amdgcn_mfma_f32_16x16x32_f16(             \
                _af[mi], _bf[ni], acc[mi][ni], 0, 0, 0);                      \
    __builtin_amdgcn_s_setprio(0);                                            \
} while (0)

#define WAITV(n) asm volatile("s_waitcnt vmcnt(" #n ")" ::: "memory")
#define BAR()    do { asm volatile("" ::: "memory");                          \
                      __builtin_amdgcn_s_barrier();                           \
                      asm volatile("" ::: "memory"); } while (0)

    const int NT = K_DIM / 32;   // 128

    // prologue: slots 0,1 <- tiles 0,1
    STAGE(0, 0);
    STAGE(1, 1);

    // main loop: 126 tiles, static x3 slot rotation (126 = 3*42)
    for (int kt = 0; kt < NT - 2; kt += 3) {
        STAGE(2, kt + 2);
        WAITV(8);                 // tile kt landed (8 newer stay in flight)
        BAR();
        MFMA_STEP(0);
        BAR();                    // all reads of slot0 done before overwrite

        STAGE(0, kt + 3);
        WAITV(8);                 // tile kt+1 landed
        BAR();
        MFMA_STEP(1);
        BAR();

        STAGE(1, kt + 4);
        WAITV(8);                 // tile kt+2 landed
        BAR();
        MFMA_STEP(2);
        BAR();
    }
    // tail: tiles 126 (slot0), 127 (slot1); no more staging
    WAITV(4);                     // tile 126 landed
    BAR();
    MFMA_STEP(0);
    WAITV(0);                     // tile 127 landed
    BAR();
    MFMA_STEP(1);

    // epilogue: per-column scale, f32 store
#pragma unroll
    for (int ni = 0; ni < 4; ++ni) {
        const int col = bn0 + wc * 64 + ni * 16 + lr;
        const float s = WS[col];
#pragma unroll
        for (int mi = 0; mi < 8; ++mi) {
            const int row = bm0 + wr * 128 + mi * 16 + lq * 4;
#pragma unroll
            for (int i = 0; i < 4; ++i) {
                Out[(size_t)(row + i) * N_DIM + col] = acc[mi][ni][i] * s;
            }
        }
    }
#undef STAGE
#undef MFMA_STEP
#undef WAITV
#undef BAR
}

extern "C" void kernel_launch(void* const* d_in, const int* in_sizes, int n_in,
                              void* d_out, int out_size, void* d_ws, size_t ws_size,
                              hipStream_t stream) {
    const float* X  = (const float*)d_in[0];
    const int*   WP = (const int*)d_in[1];
    const float* WS = (const float*)d_in[2];
    float*       Out = (float*)d_out;

    unsigned short* Xh = (unsigned short*)d_ws;
    unsigned*       Wt = (unsigned*)((char*)d_ws + WS_XH_BYTES);

    cvt_x_kernel<<<(M_DIM * K_DIM) / (256 * 8), 256, 0, stream>>>(X, Xh);
    dim3 gdq(N_DIM / 64, KH / 64);                    // 172 x 32
    dqt_kernel<<<gdq, 256, 0, stream>>>(WP, Wt);
    dim3 grid((N_DIM / 256) * (M_DIM / 256));         // 43 * 16 = 688
    qgemm4_kernel<<<grid, 512, 0, stream>>>(Xh, Wt, WS, Out);
}